// Round 8
// baseline (124.695 us; speedup 1.0000x reference)
//
#include <hip/hip_runtime.h>
#include <stdint.h>

// 7x7 conv, stride 1, pad 3, on 64 x 512 x 512 fp32 (single channel).
// out[n,y,x] = sum_{ky,kx} x[n, y+ky-3, x+kx-3] * w[ky,kx]
//
// R15: BARRIER-FREE wave-private tiles + XCD swizzle.
//   - R7..R14 post-mortem: every variant ~35-44us with VALUBusy ~= 37%
//     == (per-wave 1900 VALU cyc x 16 waves/SIMD) / 84k cyc. Per-wave stall
//     ~2/3 of life; occupancy/ILP/conflict knobs all null. The untested
//     invariant: the block-wide __syncthreads convoy (4 waves stall on the
//     same vmcnt(0) drain, compute together, phase-locked memory bursts).
//   - Fix: each wave owns its 4x256 outputs AND a private 10-row x 264-col
//     LDS region (10,560 B). Stage own rows (10 full-exec global_load_lds,
//     gy guard wave-uniform; 20 edge f4s via lanes 0..19 VGPR path), then
//     s_waitcnt vmcnt(0) on OWN loads only. NO __syncthreads anywhere:
//     waves self-pace, CU always has read-issuers and FMA-issuers.
//   - Row overlap between waves re-stages 2.5x (L2 reads, not HBM). XCD
//     swizzle maps each XCD 16 complete y-strips -> overlap/halo re-reads
//     are home-L2 hits (strip set ~3.2 MB < 4 MB XCD L2).
//   - LDS 42,240 B/block -> 3 blocks/CU = 12 independent waves/CU.
//   - Compute body / laundered b64 / FMA order / stores identical to R14.

#define IMG_W 512
#define IMG_H 512
#define NIMG  64
#define TW    256            // output cols per block (64 lanes x 4)
#define TH    16             // output rows per block (4 waves x 4)
#define HALO  3
#define WROWS 10             // input rows per wave region
#define RW    264            // floats per region row: col c <-> gx = bx-4+c
#define WREG  (WROWS * RW)   // 2640 floats = 10,560 B per wave

// async 16B global -> LDS (dest must be uniform base + lane*16, FULL exec)
__device__ __forceinline__ void gload_lds16(const float* src, float* dst_lds)
{
    __builtin_amdgcn_global_load_lds(
        (__attribute__((address_space(1))) void*)(uintptr_t)src,
        (__attribute__((address_space(3))) void*)(uintptr_t)dst_lds,
        16, 0, 0);
}

__global__ __launch_bounds__(256, 3) void conv7x7_kernel(
    const float* __restrict__ x,
    const float* __restrict__ wgt,
    float* __restrict__ out)
{
    __shared__ float lds[4 * WREG];   // 42,240 B, 4 wave-private regions

    const int tid  = threadIdx.x;
    const int wave = tid >> 6;
    const int lane = tid & 63;

    // ---- XCD-aware remap (bijective: 4096 = 8 x 512). Consecutive hw ids
    // round-robin XCDs; after remap each XCD owns 16 complete column-strips
    // (strip = one (n, x-half), ty = 0..31 consecutive).
    const int id = blockIdx.x;
    const int l  = (id & 7) * 512 + (id >> 3);
    const int ty = l & 31;
    const int s  = l >> 5;
    const int bx = (s & 1) * TW;
    const int n  = s >> 1;
    const int by = ty * TH;

    const float* img = x + (size_t)n * (IMG_W * IMG_H);
    float* o = out + (size_t)n * (IMG_W * IMG_H);

    // ---- weights: wave-uniform -> SGPRs (s_loads overlap staging) ----
    float w[49];
    #pragma unroll
    for (int i = 0; i < 49; ++i) w[i] = wgt[i];

    float* reg = &lds[wave * WREG];
    const int gy0 = by + wave * 4 - HALO;   // global y of region row 0

    // ---- edge f4s: 10 rows x {left,right}, lanes 0..19 (VGPR path) ----
    const bool edge = (lane < 2 * WROWS);
    const int  er   = lane >> 1;
    const int  es   = lane & 1;
    float4 ev = make_float4(0.f, 0.f, 0.f, 0.f);
    if (edge) {
        const int gx = es ? (bx + TW) : (bx - 4);   // fully OOB or fully in
        const int gy = gy0 + er;
        if (((unsigned)gy < IMG_H) && ((unsigned)gx < IMG_W))
            ev = *(const float4*)&img[(size_t)gy * IMG_W + gx];
    }

    // ---- stage own 10 rows: full-exec global_load_lds (gy wave-uniform) ----
    // cols 4..259 (c4 = 1..64): gx = bx + 4*lane, always in-bounds in x.
    #pragma unroll
    for (int r = 0; r < WROWS; ++r) {
        const int gy = gy0 + r;
        float* dst = reg + r * RW + 4 + 4 * lane;
        if ((unsigned)gy < IMG_H)
            gload_lds16(&img[(size_t)gy * IMG_W + bx + 4 * lane], dst);
        else
            *(float4*)dst = make_float4(0.f, 0.f, 0.f, 0.f);  // zero row
    }

    // Own-wave DMA + edge loads complete; no cross-wave deps -> NO barrier.
    asm volatile("s_waitcnt vmcnt(0)" ::: "memory");

    if (edge)
        *(float4*)(reg + er * RW + (es ? (RW - 4) : 0)) = ev;

    asm volatile("s_waitcnt lgkmcnt(0)" ::: "memory");  // edge writes visible

    // ---- compute: 4x x 4y outputs, 6 laundered ds_read_b64 per row,
    //      2-deep register row pipeline (from R14) ----
    int d[6];
    #pragma unroll
    for (int t = 0; t < 6; ++t) {
        d[t] = t * 8;
        asm volatile("" : "+v"(d[t]));
    }

    const char* tb = (const char*)reg + (size_t)lane * 16;

    float acc[4][4] = {};
    float2 q[2][6];

    #pragma unroll
    for (int u = 0; u < 6; ++u)
        q[0][u] = *(const float2*)(tb + d[u]);

    #pragma unroll
    for (int r = 0; r < 10; ++r) {
        if (r < 9) {
            const char* rowb = tb + (size_t)(r + 1) * (RW * 4);
            #pragma unroll
            for (int u = 0; u < 6; ++u)
                q[(r + 1) & 1][u] = *(const float2*)(rowb + d[u]);
        }

        const float2* qc = q[r & 1];
        const float row[12] = {qc[0].x, qc[0].y, qc[1].x, qc[1].y,
                               qc[2].x, qc[2].y, qc[3].x, qc[3].y,
                               qc[4].x, qc[4].y, qc[5].x, qc[5].y};
        #pragma unroll
        for (int j = 0; j < 4; ++j) {
            const int ky = r - j;
            if (ky >= 0 && ky < 7) {
                #pragma unroll
                for (int kx = 0; kx < 7; ++kx) {
                    const float wv = w[ky * 7 + kx];
                    #pragma unroll
                    for (int cc = 0; cc < 4; ++cc)
                        acc[j][cc] = fmaf(row[1 + kx + cc], wv, acc[j][cc]);
                }
            }
        }
    }

    // ---- store: 4 rows of float4 per thread (contiguous per wave) ----
    #pragma unroll
    for (int j = 0; j < 4; ++j) {
        float4 v = make_float4(acc[j][0], acc[j][1], acc[j][2], acc[j][3]);
        *(float4*)&o[(size_t)(by + wave * 4 + j) * IMG_W + bx + lane * 4] = v;
    }
}

extern "C" void kernel_launch(void* const* d_in, const int* in_sizes, int n_in,
                              void* d_out, int out_size, void* d_ws, size_t ws_size,
                              hipStream_t stream)
{
    const float* x   = (const float*)d_in[0];
    const float* wgt = (const float*)d_in[1];
    float* out       = (float*)d_out;

    dim3 grid(4096);   // 1D; in-kernel XCD-aware remap -> (n, ty, tx)
    conv7x7_kernel<<<grid, 256, 0, stream>>>(x, wgt, out);
}

// Round 9
// 120.547 us; speedup vs baseline: 1.0344x; 1.0344x over previous
//
#include <hip/hip_runtime.h>
#include <stdint.h>

// 7x7 conv, stride 1, pad 3, on 64 x 512 x 512 fp32 (single channel).
// out[n,y,x] = sum_{ky,kx} x[n, y+ky-3, x+kx-3] * w[ky,kx]
//
// R16: R10 (best, ~34.6us conv) with TH=16 -> 32: 8 output rows per thread.
//   - 9-probe ledger: occupancy/ILP/barrier/convoy knobs all NULL; real
//     effects only (a) LDS staging = minimal HBM traffic (R13 converse
//     proof), (b) b64 > b128 reads (+15%). So push the remaining ARITHMETIC
//     lever: halo amortization in y.
//   - TH=32: staged rows per output 22/16 -> 38/32 (-14% staging); LDS
//     reads per 8 output rows 120 -> 84 b64 (-30%); FMA per output
//     unchanged; 2048 blocks (8/CU of work, half the per-CU block
//     serialization events).
//   - LDS 38 x 264 x 4 = 40,128 B -> 4 blocks/CU (160,512 < 163,840 B),
//     16 waves/CU. __launch_bounds__(256,4) caps at 128 VGPR (est ~85).
//   - Staging (full-exec global_load_lds, wave-uniform gy guard), edge
//     path, laundered ds_read_b64, per-output FMA order: identical to R10.

#define IMG_W 512
#define IMG_H 512
#define NIMG  64
#define TW    256            // output tile width per block
#define TH    32             // output tile height per block (4 waves x 8)
#define HALO  3
#define LDS_W 264            // floats per row: tile col c <-> global x = bx-4+c
#define LDS_H (TH + 2*HALO)  // 38 rows
#define NROWS 14             // input rows read per thread (8 outputs + 6 halo)

// async 16B global -> LDS (dest must be uniform base + lane*16, FULL exec)
__device__ __forceinline__ void gload_lds16(const float* src, float* dst_lds)
{
    __builtin_amdgcn_global_load_lds(
        (__attribute__((address_space(1))) void*)(uintptr_t)src,
        (__attribute__((address_space(3))) void*)(uintptr_t)dst_lds,
        16, 0, 0);
}

__global__ __launch_bounds__(256, 4) void conv7x7_kernel(
    const float* __restrict__ x,
    const float* __restrict__ wgt,
    float* __restrict__ out)
{
    __shared__ float tile[LDS_H * LDS_W];   // 40,128 B, linear

    const int tid  = threadIdx.x;
    const int wave = tid >> 6;
    const int lane = tid & 63;
    const int bx   = blockIdx.x * TW;
    const int by   = blockIdx.y * TH;
    const int n    = blockIdx.z;

    const float* img = x + (size_t)n * (IMG_W * IMG_H);

    // ---- weights: wave-uniform -> SGPRs (s_loads overlap staging) ----
    float w[49];
    #pragma unroll
    for (int i = 0; i < 49; ++i) w[i] = wgt[i];

    // ---- stage interior: per row, one full wave, cols 4..259 ----
    // gx = bx + 4*lane in [bx, bx+255]: always in-bounds in x.
    // gy guard is wave-uniform -> exec stays full for every global_load_lds.
    for (int r = wave; r < LDS_H; r += 4) {
        const int gy = by - HALO + r;
        float* dst = &tile[r * LDS_W + 4 + 4 * lane];
        if ((unsigned)gy < IMG_H) {
            gload_lds16(&img[(size_t)gy * IMG_W + bx + 4 * lane], dst);
        } else {
            *(float4*)dst = make_float4(0.f, 0.f, 0.f, 0.f);  // contiguous write
        }
    }

    // ---- stage edges: 2 halo f4 per row (cols 0..3 and 260..263) ----
    if (tid < 2 * LDS_H) {
        const int r    = tid >> 1;
        const int side = tid & 1;
        const int cb   = side ? (LDS_W - 4) : 0;   // float col base in tile
        const int gx   = side ? (bx + 256) : (bx - 4);
        const int gy   = by - HALO + r;
        float4 v = make_float4(0.f, 0.f, 0.f, 0.f);
        if (((unsigned)gy < IMG_H) && ((unsigned)gx < IMG_W))
            v = *(const float4*)&img[(size_t)gy * IMG_W + gx];
        *(float4*)&tile[r * LDS_W + cb] = v;
    }

    __syncthreads();   // drains vmcnt (global_load_lds) + lgkmcnt

    // ---- compute: 4x x 8y outputs per thread, 6 ds_read_b64 per row,
    //      2-deep register row pipeline ----
    const int lx = lane * 4;        // output x within tile
    const int rbase = wave * 8;     // first output row (within tile outputs)

    // Laundered 8-byte deltas: opaque to the vectorizer -> loads stay as
    // individual ds_read_b64 (the conflict-free width), not re-merged b128.
    int d[6];
    #pragma unroll
    for (int t = 0; t < 6; ++t) {
        d[t] = t * 8;
        asm volatile("" : "+v"(d[t]));
    }

    // tile row (rbase + r) holds input gy = by + rbase + r - 3;
    // output j needs ky = r - j in [0,7) -> r = 0..13.
    const char* tb = (const char*)tile + (size_t)(rbase * LDS_W + lx) * 4;

    float acc[8][4] = {};
    float2 q[2][6];

    // prologue: load row 0 into q[0]
    #pragma unroll
    for (int u = 0; u < 6; ++u)
        q[0][u] = *(const float2*)(tb + d[u]);

    #pragma unroll
    for (int r = 0; r < NROWS; ++r) {
        // prefetch row r+1 into the alternate buffer before consuming row r
        if (r < NROWS - 1) {
            const char* rowb = tb + (size_t)(r + 1) * (LDS_W * 4);
            #pragma unroll
            for (int u = 0; u < 6; ++u)
                q[(r + 1) & 1][u] = *(const float2*)(rowb + d[u]);
        }

        const float2* qc = q[r & 1];
        const float row[12] = {qc[0].x, qc[0].y, qc[1].x, qc[1].y,
                               qc[2].x, qc[2].y, qc[3].x, qc[3].y,
                               qc[4].x, qc[4].y, qc[5].x, qc[5].y};
        #pragma unroll
        for (int j = 0; j < 8; ++j) {
            const int ky = r - j;
            if (ky >= 0 && ky < 7) {
                #pragma unroll
                for (int kx = 0; kx < 7; ++kx) {
                    const float wv = w[ky * 7 + kx];
                    #pragma unroll
                    for (int cc = 0; cc < 4; ++cc)
                        acc[j][cc] = fmaf(row[1 + kx + cc], wv, acc[j][cc]);
                }
            }
        }
    }

    // ---- store: 8 rows of float4 per thread (contiguous per wave) ----
    float* o = out + (size_t)n * (IMG_W * IMG_H);
    #pragma unroll
    for (int j = 0; j < 8; ++j) {
        float4 v = make_float4(acc[j][0], acc[j][1], acc[j][2], acc[j][3]);
        *(float4*)&o[(size_t)(by + rbase + j) * IMG_W + bx + lx] = v;
    }
}

extern "C" void kernel_launch(void* const* d_in, const int* in_sizes, int n_in,
                              void* d_out, int out_size, void* d_ws, size_t ws_size,
                              hipStream_t stream)
{
    const float* x   = (const float*)d_in[0];
    const float* wgt = (const float*)d_in[1];
    float* out       = (float*)d_out;

    // x: 512/256 = 2, y: 512/32 = 16, z: 64 -> 2048 blocks of 256 threads
    dim3 grid(IMG_W / TW, IMG_H / TH, NIMG);
    conv7x7_kernel<<<grid, 256, 0, stream>>>(x, wgt, out);
}